// Round 6
// baseline (268.102 us; speedup 1.0000x reference)
//
#include <hip/hip_runtime.h>

#define S_LEN 2048
#define D_MODEL 1024
#define NH 16
#define DH 64
#define WP 520  // W-tile LDS pitch in shorts (1040 B): uniform banks for b128

typedef __bf16 bf16x8 __attribute__((ext_vector_type(8)));
typedef __bf16 bf16x4 __attribute__((ext_vector_type(4)));
typedef float f32x4 __attribute__((ext_vector_type(4)));

__device__ __forceinline__ unsigned short f2bf(float f) {
  unsigned int x = __float_as_uint(f);
  x += 0x7fffu + ((x >> 16) & 1u);  // RNE
  return (unsigned short)(x >> 16);
}

__device__ __forceinline__ bf16x4 cvt4(f32x4 v) {
  return __builtin_convertvector(v, bf16x4);
}

__device__ __forceinline__ float exp2raw(float x) {
#if __has_builtin(__builtin_amdgcn_exp2f)
  return __builtin_amdgcn_exp2f(x);
#else
  return exp2f(x);
#endif
}

__device__ __forceinline__ f32x4 mfma16(bf16x8 a, bf16x8 b, f32x4 c) {
  return __builtin_amdgcn_mfma_f32_16x16x32_bf16(a, b, c, 0, 0, 0);
}

__device__ __forceinline__ void gl2lds(const unsigned short* g, unsigned short* l) {
  __builtin_amdgcn_global_load_lds(
      (__attribute__((address_space(1))) void*)g,
      (__attribute__((address_space(3))) void*)l, 16, 0, 0);
}

// ---- fused prep: pack mask bits (blocks 0..32767) + fp32->bf16 convert ----
__global__ __launch_bounds__(256) void prep_kernel(
    const float* __restrict__ q, const float* __restrict__ wq,
    const float* __restrict__ wk, const float* __restrict__ wv,
    const float* __restrict__ wo, const int* __restrict__ mask,
    unsigned short* __restrict__ qbf, unsigned short* __restrict__ wbf,
    unsigned long long* __restrict__ bits) {
  const int bx = blockIdx.x;
  if (bx < 32768) {  // pack mask: 1 bit per (b,q,key), lane i <-> bit i
    int i = bx * 256 + threadIdx.x;
    unsigned long long bal = __ballot(mask[i] != 0);
    if ((threadIdx.x & 63) == 0) bits[i >> 6] = bal;
  } else {  // convert 8 floats per thread
    const long t = (long)(bx - 32768) * 256 + threadIdx.x;
    const float* src;
    unsigned short* dst;
    long e;
    if (t < 524288) { src = q; dst = qbf; e = t * 8; }
    else {
      long u = t - 524288;
      int wi = (int)(u >> 17);
      e = (u & 131071) * 8;
      src = wi == 0 ? wq : wi == 1 ? wk : wi == 2 ? wv : wo;
      dst = wbf + (long)wi * 1048576;
    }
    float4 a = *(const float4*)(src + e);
    float4 b = *(const float4*)(src + e + 4);
    ushort4 p0 = {f2bf(a.x), f2bf(a.y), f2bf(a.z), f2bf(a.w)};
    ushort4 p1 = {f2bf(b.x), f2bf(b.y), f2bf(b.z), f2bf(b.w)};
    *(ushort4*)(dst + e) = p0;
    *(ushort4*)(dst + e + 4) = p1;
  }
}

// ---- barrier-free-K GEMM: C = A(4096x1024) @ [Wq;Wk;Wv](3072x1024)^T ----
// Block = 256m x 64n (one head col-block), 4 waves each 64m x 64n, acc[4][4].
// W phase-tile (64n x 512k) in LDS at pitch WP (1 gl2lds per row, no swizzle);
// inner K-loop: A-frags direct from global (L2-hot), B from LDS, NO barriers.
__global__ __launch_bounds__(256, 2) void gemm_qkv(
    const unsigned short* __restrict__ A, const unsigned short* __restrict__ W3,
    unsigned short* __restrict__ qb, unsigned short* __restrict__ kb,
    unsigned short* __restrict__ vt, float qscale) {
  __shared__ __align__(16) unsigned short Ws[64 * WP];  // 65 KB
  const int tid = threadIdx.x, lane = tid & 63, wid = tid >> 6;
  const int quad = lane >> 4, c = lane & 15;
  const int nG = blockIdx.x * 64;
  const int wi = nG >> 10, nn0 = nG & 1023;
  const int hh = nn0 >> 6;
  const int m0 = blockIdx.y * 256;
  const unsigned short* Wsrc =
      W3 + (size_t)wi * 1048576 + (size_t)nn0 * 1024 + lane * 8;
  f32x4 acc[4][4] = {};
#pragma unroll
  for (int p = 0; p < 2; ++p) {
    // stage: wave w rows [w*16, w*16+16); one glds per row (64 lanes x 16B)
#pragma unroll
    for (int i = 0; i < 16; ++i) {
      const int row = wid * 16 + i;
      gl2lds(Wsrc + (size_t)row * 1024 + p * 512, &Ws[row * WP]);
    }
    __syncthreads();
#pragma unroll 4
    for (int kc = 0; kc < 16; ++kc) {
      bf16x8 a[4], b[4];
#pragma unroll
      for (int mt = 0; mt < 4; ++mt)
        a[mt] = *(const bf16x8*)(A +
                                 (size_t)(m0 + wid * 64 + mt * 16 + c) * 1024 +
                                 p * 512 + kc * 32 + quad * 8);
#pragma unroll
      for (int nt = 0; nt < 4; ++nt)
        b[nt] = *(const bf16x8*)(&Ws[(nt * 16 + c) * WP + (kc * 4 + quad) * 8]);
#pragma unroll
      for (int mt = 0; mt < 4; ++mt)
#pragma unroll
        for (int nt = 0; nt < 4; ++nt)
          acc[mt][nt] = mfma16(a[mt], b[nt], acc[mt][nt]);
    }
    if (p == 0) __syncthreads();  // all reads of Ws done before restage
  }
  const int bb = m0 >> 11;
#pragma unroll
  for (int mt = 0; mt < 4; ++mt) {
#pragma unroll
    for (int nt = 0; nt < 4; ++nt) {
      const int ss = (m0 & 2047) + wid * 64 + mt * 16 + quad * 4;
      const int d = nt * 16 + c;
      if (wi == 0) {
#pragma unroll
        for (int r = 0; r < 4; ++r)
          qb[(size_t)((bb * NH + hh) * S_LEN + ss + r) * DH + d] =
              f2bf(acc[mt][nt][r] * qscale);
      } else if (wi == 1) {
#pragma unroll
        for (int r = 0; r < 4; ++r)
          kb[(size_t)((bb * NH + hh) * S_LEN + ss + r) * DH + d] =
              f2bf(acc[mt][nt][r]);
      } else {  // V^T: 4 regs = 4 consecutive s
        *(bf16x4*)(vt + (size_t)((bb * NH + hh) * DH + d) * S_LEN + ss) =
            cvt4(acc[mt][nt]);
      }
    }
  }
}

// ---- O projection, same barrier-free structure; fp32 out + bias ----
__global__ __launch_bounds__(256, 2) void gemm_out(
    const unsigned short* __restrict__ A, const unsigned short* __restrict__ W,
    float* __restrict__ out, const float* __restrict__ bias) {
  __shared__ __align__(16) unsigned short Ws[64 * WP];  // 65 KB
  const int tid = threadIdx.x, lane = tid & 63, wid = tid >> 6;
  const int quad = lane >> 4, c = lane & 15;
  const int n0 = blockIdx.x * 64, m0 = blockIdx.y * 256;
  const unsigned short* Wsrc = W + (size_t)n0 * 1024 + lane * 8;
  f32x4 acc[4][4] = {};
#pragma unroll
  for (int p = 0; p < 2; ++p) {
#pragma unroll
    for (int i = 0; i < 16; ++i) {
      const int row = wid * 16 + i;
      gl2lds(Wsrc + (size_t)row * 1024 + p * 512, &Ws[row * WP]);
    }
    __syncthreads();
#pragma unroll 4
    for (int kc = 0; kc < 16; ++kc) {
      bf16x8 a[4], b[4];
#pragma unroll
      for (int mt = 0; mt < 4; ++mt)
        a[mt] = *(const bf16x8*)(A +
                                 (size_t)(m0 + wid * 64 + mt * 16 + c) * 1024 +
                                 p * 512 + kc * 32 + quad * 8);
#pragma unroll
      for (int nt = 0; nt < 4; ++nt)
        b[nt] = *(const bf16x8*)(&Ws[(nt * 16 + c) * WP + (kc * 4 + quad) * 8]);
#pragma unroll
      for (int mt = 0; mt < 4; ++mt)
#pragma unroll
        for (int nt = 0; nt < 4; ++nt)
          acc[mt][nt] = mfma16(a[mt], b[nt], acc[mt][nt]);
    }
    if (p == 0) __syncthreads();
  }
#pragma unroll
  for (int mt = 0; mt < 4; ++mt) {
#pragma unroll
    for (int nt = 0; nt < 4; ++nt) {
      const int mb = m0 + wid * 64 + mt * 16 + quad * 4;
      const int n = n0 + nt * 16 + c;
      const float bv = bias[n];
#pragma unroll
      for (int r = 0; r < 4; ++r)
        out[(size_t)(mb + r) * D_MODEL + n] = acc[mt][nt][r] + bv;
    }
  }
}

// ---- flash attention, static-max softmax (unchanged from R4, passing) ----
__global__ __launch_bounds__(256, 4) void attn_kernel(
    const unsigned short* __restrict__ qb, const unsigned short* __restrict__ kb,
    const unsigned short* __restrict__ vt,
    const unsigned long long* __restrict__ mbits,
    unsigned short* __restrict__ ctx) {
  const int h = blockIdx.x, qt = blockIdx.y, b = blockIdx.z;
  const int bh = b * NH + h;
  const int tid = threadIdx.x, lane = tid & 63, wid = tid >> 6;
  const int quad = lane >> 4, c = lane & 15, cx = c & 7;
  const int qw = wid & 1, kh = wid >> 1;
  const int q0 = qt * 64;
  __shared__ __align__(16) unsigned short KV[4][4096];  // Ks0,Ks1,Vs0,Vs1 32KB

  const int qA = q0 + qw * 32 + c;
  const unsigned short* qpA = qb + (size_t)(bh * S_LEN + qA) * DH;
  bf16x8 bq[2][2];
  bq[0][0] = *(const bf16x8*)(qpA + quad * 8);
  bq[0][1] = *(const bf16x8*)(qpA + 32 + quad * 8);
  bq[1][0] = *(const bf16x8*)(qpA + 16 * DH + quad * 8);
  bq[1][1] = *(const bf16x8*)(qpA + 16 * DH + 32 + quad * 8);

  f32x4 o[2][4] = {};
  float lacc[2] = {0.f, 0.f};
  const unsigned long long* mq[2];
  mq[0] = mbits + (size_t)(b * S_LEN + qA) * 32 + kh * 16;
  mq[1] = mq[0] + 16 * 32;

  const int srow = lane >> 3, schk = ((lane & 7) ^ srow) * 8;
  const unsigned short* Ksh = KV[kh];
  const unsigned short* Vsh = KV[2 + kh];
  unsigned short* Pw = &KV[0][0] + wid * 1152;  // aliases Ks (dead after QK)

  const unsigned short* gK =
      kb + (size_t)(bh * S_LEN + (wid & 1) * 1024 + srow) * DH + schk;
  const unsigned short* gV =
      vt + (size_t)(bh * DH + srow) * S_LEN + (wid - 2) * 1024 + schk;

  for (int kt = 0; kt < 1024; kt += 64) {
    if (wid < 2) {
#pragma unroll
      for (int i = 0; i < 8; ++i)
        gl2lds(gK + (size_t)(kt + i * 8) * DH, &KV[wid][i * 512]);
    } else {
#pragma unroll
      for (int i = 0; i < 8; ++i)
        gl2lds(gV + (size_t)(i * 8) * S_LEN + kt, &KV[wid][i * 512]);
    }
    __syncthreads();  // (1) staging done

    f32x4 s[2][4];
#pragma unroll
    for (int g = 0; g < 4; ++g) {
      const int rho = g * 16 + c;
      bf16x8 k0 = *(const bf16x8*)(&Ksh[rho * 64 + (quad ^ cx) * 8]);
      bf16x8 k1 = *(const bf16x8*)(&Ksh[rho * 64 + ((4 + quad) ^ cx) * 8]);
      f32x4 z = {};
      z = mfma16(k0, bq[0][0], z);
      z = mfma16(k1, bq[0][1], z);
      s[0][g] = z;
      f32x4 y = {};
      y = mfma16(k0, bq[1][0], y);
      y = mfma16(k1, bq[1][1], y);
      s[1][g] = y;
    }
    __syncthreads();  // (2) QK reads done; Ks reusable for P

    const int mi = kt >> 6;
    bf16x8 bp[2][2];
#pragma unroll
    for (int sub = 0; sub < 2; ++sub) {
      const unsigned long long w64 = mq[sub][mi];
      const unsigned int wlo = (unsigned int)w64;
      const unsigned int whi = (unsigned int)(w64 >> 32);
      float lp = 0.f;
#pragma unroll
      for (int g = 0; g < 4; ++g) {
        const unsigned int bits =
            ((g & 2) ? whi : wlo) >> ((g & 1) * 16 + quad * 4);
        f32x4 p;
#pragma unroll
        for (int r = 0; r < 4; ++r) {
          const float e = exp2raw(s[sub][g][r]);
          p[r] = ((bits >> r) & 1u) ? 0.f : e;
          lp += p[r];
        }
        *(bf16x4*)(&Pw[c * 72 + g * 16 + quad * 4]) = cvt4(p);
      }
      lacc[sub] += lp;
      bp[sub][0] = *(const bf16x8*)(&Pw[c * 72 + quad * 8]);
      bp[sub][1] = *(const bf16x8*)(&Pw[c * 72 + 32 + quad * 8]);
    }

#pragma unroll
    for (int ks = 0; ks < 2; ++ks) {
#pragma unroll
      for (int nt = 0; nt < 4; ++nt) {
        bf16x8 av = *(const bf16x8*)(
            &Vsh[(nt * 16 + c) * 64 + ((ks * 4 + quad) ^ cx) * 8]);
        o[0][nt] = mfma16(av, bp[0][ks], o[0][nt]);
        o[1][nt] = mfma16(av, bp[1][ks], o[1][nt]);
      }
    }
    __syncthreads();  // (3) P/V consumed; safe to restage
  }

#pragma unroll
  for (int sub = 0; sub < 2; ++sub) {
    lacc[sub] += __shfl_xor(lacc[sub], 16, 64);
    lacc[sub] += __shfl_xor(lacc[sub], 32, 64);
  }

  float* mrg = (float*)&KV[0][0];
  float* ml = mrg + 4 * 16 * 68;
  if (kh == 1) {
#pragma unroll
    for (int sub = 0; sub < 2; ++sub) {
      float* mo = mrg + (qw * 2 + sub) * 1088;
#pragma unroll
      for (int nt = 0; nt < 4; ++nt)
        *(f32x4*)(mo + c * 68 + nt * 16 + quad * 4) = o[sub][nt];
      if (quad == 0) ml[(qw * 2 + sub) * 16 + c] = lacc[sub];
    }
  }
  __syncthreads();
  if (kh == 0) {
#pragma unroll
    for (int sub = 0; sub < 2; ++sub) {
      const int pp = qw * 2 + sub;
      const float inv = 1.0f / (lacc[sub] + ml[pp * 16 + c]);
      const int q = q0 + qw * 32 + sub * 16 + c;
      const float* mo = mrg + pp * 1088;
#pragma unroll
      for (int nt = 0; nt < 4; ++nt) {
        f32x4 ob = *(const f32x4*)(mo + c * 68 + nt * 16 + quad * 4);
        f32x4 rr = (o[sub][nt] + ob) * inv;
        *(bf16x4*)(ctx + (size_t)(b * S_LEN + q) * D_MODEL + h * DH + nt * 16 +
                   quad * 4) = cvt4(rr);
      }
    }
  }
}

extern "C" void kernel_launch(void* const* d_in, const int* in_sizes, int n_in,
                              void* d_out, int out_size, void* d_ws, size_t ws_size,
                              hipStream_t stream) {
  const float* query = (const float*)d_in[0];
  const int* mask = (const int*)d_in[1];
  const float* Wq = (const float*)d_in[2];
  const float* Wk = (const float*)d_in[3];
  const float* Wv = (const float*)d_in[4];
  const float* Wo = (const float*)d_in[5];
  const float* bo = (const float*)d_in[6];
  float* out = (float*)d_out;

  char* ws = (char*)d_ws;
  const size_t MB = 1024 * 1024;
  unsigned short* qbf = (unsigned short*)(ws);           // 8 MB; reused as ctx
  unsigned short* wbf = (unsigned short*)(ws + 8 * MB);  // 8 MB (Wq,Wk,Wv,Wo bf16)
  unsigned short* qb = (unsigned short*)(ws + 16 * MB);  // 8 MB
  unsigned short* kb = (unsigned short*)(ws + 24 * MB);  // 8 MB
  unsigned short* vt = (unsigned short*)(ws + 32 * MB);  // 8 MB
  unsigned long long* mb = (unsigned long long*)(ws + 40 * MB);  // 1 MB
  unsigned short* ctx = qbf;

  prep_kernel<<<32768 + 4096, 256, 0, stream>>>(query, Wq, Wk, Wv, Wo, mask,
                                                qbf, wbf, mb);

  // Q scaled by 1/sqrt(dh) * log2(e): softmax in exp2 domain
  gemm_qkv<<<dim3(3072 / 64, 4096 / 256), 256, 0, stream>>>(
      qbf, wbf, qb, kb, vt, 0.18033688f);

  attn_kernel<<<dim3(NH, S_LEN / 64, 2), 256, 0, stream>>>(qb, kb, vt, mb, ctx);

  gemm_out<<<dim3(1024 / 64, 4096 / 256), 256, 0, stream>>>(
      ctx, wbf + 3 * 1048576, out, bo);
}

// Round 7
// 224.331 us; speedup vs baseline: 1.1951x; 1.1951x over previous
//
#include <hip/hip_runtime.h>

#define S_LEN 2048
#define D_MODEL 1024
#define NH 16
#define DH 64

typedef __bf16 bf16x8 __attribute__((ext_vector_type(8)));
typedef __bf16 bf16x4 __attribute__((ext_vector_type(4)));
typedef float f32x4 __attribute__((ext_vector_type(4)));

__device__ __forceinline__ unsigned short f2bf(float f) {
  unsigned int x = __float_as_uint(f);
  x += 0x7fffu + ((x >> 16) & 1u);  // RNE
  return (unsigned short)(x >> 16);
}

__device__ __forceinline__ bf16x4 cvt4(f32x4 v) {
  return __builtin_convertvector(v, bf16x4);
}

__device__ __forceinline__ float exp2raw(float x) {
#if __has_builtin(__builtin_amdgcn_exp2f)
  return __builtin_amdgcn_exp2f(x);
#else
  return exp2f(x);
#endif
}

__device__ __forceinline__ f32x4 mfma16(bf16x8 a, bf16x8 b, f32x4 c) {
  return __builtin_amdgcn_mfma_f32_16x16x32_bf16(a, b, c, 0, 0, 0);
}

__device__ __forceinline__ void gl2lds(const unsigned short* g, unsigned short* l) {
  __builtin_amdgcn_global_load_lds(
      (__attribute__((address_space(1))) void*)g,
      (__attribute__((address_space(3))) void*)l, 16, 0, 0);
}

// ---- fused prep: pack mask bits (blocks 0..32767) + fp32->bf16 convert ----
__global__ __launch_bounds__(256) void prep_kernel(
    const float* __restrict__ q, const float* __restrict__ wq,
    const float* __restrict__ wk, const float* __restrict__ wv,
    const float* __restrict__ wo, const int* __restrict__ mask,
    unsigned short* __restrict__ qbf, unsigned short* __restrict__ wbf,
    unsigned long long* __restrict__ bits) {
  const int bx = blockIdx.x;
  if (bx < 32768) {  // pack mask: 1 bit per (b,q,key), lane i <-> bit i
    int i = bx * 256 + threadIdx.x;
    unsigned long long bal = __ballot(mask[i] != 0);
    if ((threadIdx.x & 63) == 0) bits[i >> 6] = bal;
  } else {  // convert 8 floats per thread
    const long t = (long)(bx - 32768) * 256 + threadIdx.x;
    const float* src;
    unsigned short* dst;
    long e;
    if (t < 524288) { src = q; dst = qbf; e = t * 8; }
    else {
      long u = t - 524288;
      int wi = (int)(u >> 17);
      e = (u & 131071) * 8;
      src = wi == 0 ? wq : wi == 1 ? wk : wi == 2 ? wv : wo;
      dst = wbf + (long)wi * 1048576;
    }
    float4 a = *(const float4*)(src + e);
    float4 b = *(const float4*)(src + e + 4);
    ushort4 p0 = {f2bf(a.x), f2bf(a.y), f2bf(a.z), f2bf(a.w)};
    ushort4 p1 = {f2bf(b.x), f2bf(b.y), f2bf(b.z), f2bf(b.w)};
    *(ushort4*)(dst + e) = p0;
    *(ushort4*)(dst + e + 4) = p1;
  }
}

// ---- fused QKV: C = A(4096x1024) @ [Wq;Wk;Wv](3072x1024)^T; BK=64 ----
// (R4 structure: 128x128 tile, 4 waves 2x2, XOR-swizzled LDS, glds width 16)
__global__ __launch_bounds__(256) void gemm_qkv(
    const unsigned short* __restrict__ A, const unsigned short* __restrict__ W3,
    unsigned short* __restrict__ qb, unsigned short* __restrict__ kb,
    unsigned short* __restrict__ vt, float qscale) {
  __shared__ unsigned short As[128 * 64];  // 16 KB
  __shared__ unsigned short Bs[128 * 64];
  const int tid = threadIdx.x, lane = tid & 63, wid = tid >> 6;
  const int wm = wid >> 1, wn = wid & 1;
  const int quad = lane >> 4, c = lane & 15, cx = c & 7;
  const int nG = blockIdx.x * 128;
  const int wi = nG >> 10, nn0 = nG & 1023;
  const int m0 = blockIdx.y * 128;
  const unsigned short* Bsrc = W3 + (size_t)wi * 1048576;
  const int srow = lane >> 3;
  const int schk = ((lane & 7) ^ srow) * 8;
  const unsigned short* ag = A + (size_t)(m0 + wid * 32 + srow) * 1024 + schk;
  const unsigned short* bg = Bsrc + (size_t)(nn0 + wid * 32 + srow) * 1024 + schk;
  f32x4 acc[4][4] = {};
  for (int kk = 0; kk < 1024; kk += 64) {
#pragma unroll
    for (int i = 0; i < 4; ++i) {
      gl2lds(ag + (size_t)(i * 8) * 1024 + kk, &As[(wid * 32 + i * 8) * 64]);
      gl2lds(bg + (size_t)(i * 8) * 1024 + kk, &Bs[(wid * 32 + i * 8) * 64]);
    }
    __syncthreads();
#pragma unroll
    for (int kc = 0; kc < 2; ++kc) {
      bf16x8 a[4], b[4];
#pragma unroll
      for (int mt = 0; mt < 4; ++mt)
        a[mt] = *(const bf16x8*)(
            &As[(wm * 64 + mt * 16 + c) * 64 + ((kc * 4 + quad) ^ cx) * 8]);
#pragma unroll
      for (int nt = 0; nt < 4; ++nt)
        b[nt] = *(const bf16x8*)(
            &Bs[(wn * 64 + nt * 16 + c) * 64 + ((kc * 4 + quad) ^ cx) * 8]);
#pragma unroll
      for (int mt = 0; mt < 4; ++mt)
#pragma unroll
        for (int nt = 0; nt < 4; ++nt)
          acc[mt][nt] = mfma16(a[mt], b[nt], acc[mt][nt]);
    }
    __syncthreads();
  }
#pragma unroll
  for (int mt = 0; mt < 4; ++mt) {
#pragma unroll
    for (int nt = 0; nt < 4; ++nt) {
      const int mb = m0 + wm * 64 + mt * 16 + quad * 4;
      const int n = nn0 + wn * 64 + nt * 16 + c;
      const int hh = n >> 6, d = n & 63;
      const int bb = mb >> 11, ss = mb & 2047;
      if (wi == 0) {
#pragma unroll
        for (int r = 0; r < 4; ++r)
          qb[(size_t)((bb * NH + hh) * S_LEN + ss + r) * DH + d] =
              f2bf(acc[mt][nt][r] * qscale);
      } else if (wi == 1) {
#pragma unroll
        for (int r = 0; r < 4; ++r)
          kb[(size_t)((bb * NH + hh) * S_LEN + ss + r) * DH + d] =
              f2bf(acc[mt][nt][r]);
      } else {  // V^T: 4 regs = 4 consecutive s
        *(bf16x4*)(vt + (size_t)((bb * NH + hh) * DH + d) * S_LEN + ss) =
            cvt4(acc[mt][nt]);
      }
    }
  }
}

// ---- O projection: out = ctx(4096x1024) @ Wo^T + bo; BK=64 (R4) ----
__global__ __launch_bounds__(256) void gemm_out(
    const unsigned short* __restrict__ A, const unsigned short* __restrict__ W,
    float* __restrict__ out, const float* __restrict__ bias) {
  __shared__ unsigned short As[128 * 64];  // 16 KB
  __shared__ unsigned short Bs[64 * 64];   // 8 KB
  const int tid = threadIdx.x, lane = tid & 63, wid = tid >> 6;
  const int wm = wid >> 1, wn = wid & 1;
  const int quad = lane >> 4, c = lane & 15, cx = c & 7;
  const int n0 = blockIdx.x * 64, m0 = blockIdx.y * 128;
  const int srow = lane >> 3;
  const int schk = ((lane & 7) ^ srow) * 8;
  const unsigned short* ag = A + (size_t)(m0 + wid * 32 + srow) * 1024 + schk;
  const unsigned short* bg = W + (size_t)(n0 + wid * 16 + srow) * 1024 + schk;
  f32x4 acc[4][2] = {};
  for (int kk = 0; kk < 1024; kk += 64) {
#pragma unroll
    for (int i = 0; i < 4; ++i)
      gl2lds(ag + (size_t)(i * 8) * 1024 + kk, &As[(wid * 32 + i * 8) * 64]);
#pragma unroll
    for (int i = 0; i < 2; ++i)
      gl2lds(bg + (size_t)(i * 8) * 1024 + kk, &Bs[(wid * 16 + i * 8) * 64]);
    __syncthreads();
#pragma unroll
    for (int kc = 0; kc < 2; ++kc) {
      bf16x8 a[4], b[2];
#pragma unroll
      for (int mt = 0; mt < 4; ++mt)
        a[mt] = *(const bf16x8*)(
            &As[(wm * 64 + mt * 16 + c) * 64 + ((kc * 4 + quad) ^ cx) * 8]);
#pragma unroll
      for (int nt = 0; nt < 2; ++nt)
        b[nt] = *(const bf16x8*)(
            &Bs[(wn * 32 + nt * 16 + c) * 64 + ((kc * 4 + quad) ^ cx) * 8]);
#pragma unroll
      for (int mt = 0; mt < 4; ++mt)
#pragma unroll
        for (int nt = 0; nt < 2; ++nt)
          acc[mt][nt] = mfma16(a[mt], b[nt], acc[mt][nt]);
    }
    __syncthreads();
  }
#pragma unroll
  for (int mt = 0; mt < 4; ++mt) {
#pragma unroll
    for (int nt = 0; nt < 2; ++nt) {
      const int mb = m0 + wm * 64 + mt * 16 + quad * 4;
      const int n = n0 + wn * 32 + nt * 16 + c;
      const float bv = bias[n];
#pragma unroll
      for (int r = 0; r < 4; ++r)
        out[(size_t)(mb + r) * D_MODEL + n] = acc[mt][nt][r] + bv;
    }
  }
}

// ---- flash attention, static-max softmax, 64 q per wave ----
// block = (head, 128 q, batch); 4 waves = 2 qwaves(64q) x 2 key-halves.
// K-frags in regs reused across 4 q-subgroups; dedicated P buffer
// (2 barriers/tile); key-half merge = plain sums (static-max softmax).
__global__ __launch_bounds__(256, 2) void attn_kernel(
    const unsigned short* __restrict__ qb, const unsigned short* __restrict__ kb,
    const unsigned short* __restrict__ vt,
    const unsigned long long* __restrict__ mbits,
    unsigned short* __restrict__ ctx) {
  const int h = blockIdx.x, qt = blockIdx.y, b = blockIdx.z;
  const int bh = b * NH + h;
  const int tid = threadIdx.x, lane = tid & 63, wid = tid >> 6;
  const int quad = lane >> 4, c = lane & 15, cx = c & 7;
  const int qw = wid & 1, kh = wid >> 1;
  const int q0 = qt * 128;
  __shared__ __align__(16) unsigned short KV[4][4096];      // 32 KB
  __shared__ __align__(16) unsigned short Pbuf[4][64 * 72];  // 36 KB

  const int qbase = q0 + qw * 64;
  const unsigned short* qp = qb + (size_t)(bh * S_LEN + qbase + c) * DH;
  bf16x8 bq[4][2];
#pragma unroll
  for (int sub = 0; sub < 4; ++sub) {
    bq[sub][0] = *(const bf16x8*)(qp + sub * 16 * DH + quad * 8);
    bq[sub][1] = *(const bf16x8*)(qp + sub * 16 * DH + 32 + quad * 8);
  }

  f32x4 o[4][4] = {};
  float lacc[4] = {0.f, 0.f, 0.f, 0.f};
  const unsigned long long* mq0 =
      mbits + (size_t)(b * S_LEN + qbase + c) * 32 + kh * 16;

  const int srow = lane >> 3, schk = ((lane & 7) ^ srow) * 8;
  const unsigned short* Ksh = KV[kh];
  const unsigned short* Vsh = KV[2 + kh];
  unsigned short* Pw = Pbuf[wid];

  const unsigned short* gK =
      kb + (size_t)(bh * S_LEN + (wid & 1) * 1024 + srow) * DH + schk;
  const unsigned short* gV =
      vt + (size_t)(bh * DH + srow) * S_LEN + (wid - 2) * 1024 + schk;

  for (int kt = 0; kt < 1024; kt += 64) {
    if (wid < 2) {
#pragma unroll
      for (int i = 0; i < 8; ++i)
        gl2lds(gK + (size_t)(kt + i * 8) * DH, &KV[wid][i * 512]);
    } else {
#pragma unroll
      for (int i = 0; i < 8; ++i)
        gl2lds(gV + (size_t)(i * 8) * S_LEN + kt, &KV[wid][i * 512]);
    }
    __syncthreads();  // (1) staging complete

    // K-tile fragments, kept in regs across all 4 q-subgroups
    bf16x8 kf[8];
#pragma unroll
    for (int g = 0; g < 4; ++g) {
      const int rho = g * 16 + c;
      kf[2 * g] = *(const bf16x8*)(&Ksh[rho * 64 + (quad ^ cx) * 8]);
      kf[2 * g + 1] = *(const bf16x8*)(&Ksh[rho * 64 + ((4 + quad) ^ cx) * 8]);
    }

    const int mi = kt >> 6;
#pragma unroll
    for (int sub = 0; sub < 4; ++sub) {
      f32x4 s[4];
#pragma unroll
      for (int g = 0; g < 4; ++g) {
        f32x4 z = {};
        z = mfma16(kf[2 * g], bq[sub][0], z);
        z = mfma16(kf[2 * g + 1], bq[sub][1], z);
        s[g] = z;
      }
      const unsigned long long w64 = mq0[sub * 512 + mi];
      const unsigned int wlo = (unsigned int)w64;
      const unsigned int whi = (unsigned int)(w64 >> 32);
      float lp = 0.f;
#pragma unroll
      for (int g = 0; g < 4; ++g) {
        const unsigned int bits =
            ((g & 2) ? whi : wlo) >> ((g & 1) * 16 + quad * 4);
        f32x4 p;
#pragma unroll
        for (int r = 0; r < 4; ++r) {
          const float e = exp2raw(s[g][r]);
          p[r] = ((bits >> r) & 1u) ? 0.f : e;
          lp += p[r];
        }
        *(bf16x4*)(&Pw[(sub * 16 + c) * 72 + g * 16 + quad * 4]) = cvt4(p);
      }
      lacc[sub] += lp;
    }

    // ctx^T += V^T · P^T  (V-frag read once, used for all 4 subgroups)
#pragma unroll
    for (int ks = 0; ks < 2; ++ks) {
      bf16x8 bp[4];
#pragma unroll
      for (int sub = 0; sub < 4; ++sub)
        bp[sub] =
            *(const bf16x8*)(&Pw[(sub * 16 + c) * 72 + ks * 32 + quad * 8]);
#pragma unroll
      for (int nt = 0; nt < 4; ++nt) {
        bf16x8 av = *(const bf16x8*)(
            &Vsh[(nt * 16 + c) * 64 + ((ks * 4 + quad) ^ cx) * 8]);
#pragma unroll
        for (int sub = 0; sub < 4; ++sub)
          o[sub][nt] = mfma16(av, bp[sub], o[sub][nt]);
      }
    }
    __syncthreads();  // (2) K/V consumed; safe to restage
  }

#pragma unroll
  for (int sub = 0; sub < 4; ++sub) {
    lacc[sub] += __shfl_xor(lacc[sub], 16, 64);
    lacc[sub] += __shfl_xor(lacc[sub], 32, 64);
  }

  // merge key-halves via Pbuf: 8 panels of 16q x 68 floats + l array
  float* mrg = (float*)&Pbuf[0][0];
  float* ml = mrg + 8 * 1088;
  if (kh == 1) {
#pragma unroll
    for (int sub = 0; sub < 4; ++sub) {
      float* mo = mrg + (qw * 4 + sub) * 1088;
#pragma unroll
      for (int nt = 0; nt < 4; ++nt)
        *(f32x4*)(mo + c * 68 + nt * 16 + quad * 4) = o[sub][nt];
      if (quad == 0) ml[(qw * 4 + sub) * 16 + c] = lacc[sub];
    }
  }
  __syncthreads();
  if (kh == 0) {
#pragma unroll
    for (int sub = 0; sub < 4; ++sub) {
      const int pp = qw * 4 + sub;
      const float inv = 1.0f / (lacc[sub] + ml[pp * 16 + c]);
      const int q = qbase + sub * 16 + c;
      const float* mo = mrg + pp * 1088;
#pragma unroll
      for (int nt = 0; nt < 4; ++nt) {
        f32x4 ob = *(const f32x4*)(mo + c * 68 + nt * 16 + quad * 4);
        f32x4 rr = (o[sub][nt] + ob) * inv;
        *(bf16x4*)(ctx + (size_t)(b * S_LEN + q) * D_MODEL + h * DH + nt * 16 +
                   quad * 4) = cvt4(rr);
      }
    }
  }
}

extern "C" void kernel_launch(void* const* d_in, const int* in_sizes, int n_in,
                              void* d_out, int out_size, void* d_ws, size_t ws_size,
                              hipStream_t stream) {
  const float* query = (const float*)d_in[0];
  const int* mask = (const int*)d_in[1];
  const float* Wq = (const float*)d_in[2];
  const float* Wk = (const float*)d_in[3];
  const float* Wv = (const float*)d_in[4];
  const float* Wo = (const float*)d_in[5];
  const float* bo = (const float*)d_in[6];
  float* out = (float*)d_out;

  char* ws = (char*)d_ws;
  const size_t MB = 1024 * 1024;
  unsigned short* qbf = (unsigned short*)(ws);           // 8 MB; reused as ctx
  unsigned short* wbf = (unsigned short*)(ws + 8 * MB);  // 8 MB (Wq,Wk,Wv,Wo bf16)
  unsigned short* qb = (unsigned short*)(ws + 16 * MB);  // 8 MB
  unsigned short* kb = (unsigned short*)(ws + 24 * MB);  // 8 MB
  unsigned short* vt = (unsigned short*)(ws + 32 * MB);  // 8 MB
  unsigned long long* mb = (unsigned long long*)(ws + 40 * MB);  // 1 MB
  unsigned short* ctx = qbf;

  prep_kernel<<<32768 + 4096, 256, 0, stream>>>(query, Wq, Wk, Wv, Wo, mask,
                                                qbf, wbf, mb);

  // Q scaled by 1/sqrt(dh) * log2(e): softmax in exp2 domain
  gemm_qkv<<<dim3(3072 / 128, 4096 / 128), 256, 0, stream>>>(
      qbf, wbf, qb, kb, vt, 0.18033688f);

  attn_kernel<<<dim3(NH, S_LEN / 128, 2), 256, 0, stream>>>(qb, kb, vt, mb,
                                                            ctx);

  gemm_out<<<dim3(1024 / 64, 4096 / 128), 256, 0, stream>>>(
      ctx, wbf + 3 * 1048576, out, bo);
}